// Round 3
// baseline (553.469 us; speedup 1.0000x reference)
//
#include <hip/hip_runtime.h>

// ---------------------------------------------------------------------------
// VeRA Linear: y = x @ (W + 4*diag(b) B diag(d) A)^T + bias
// T=8192, IN=OUT=4096, R=256, fp32 in/out.
// R6: m201-exact 8-phase schedule on the 256x256 / 8-wave / BK=64 structure.
//   Phase = one C-quadrant (32 rows x 64 cols) x full K=64:
//     {ds_reads (pre-barrier!), 1 staging unit, [vmcnt(4) at p4/p8],
//      s_barrier, lgkmcnt(0)+sched_barrier, setprio(1), 16 MFMA, setprio(0),
//      s_barrier}
//   ds_read latency hides under barrier#1 (sibling waves still in MFMA of
//   previous phase); counted vmcnt leaves exactly 2 units (4 loads) in
//   flight at each wait. Staging slots per iteration (tiles 2i,2i+1):
//     p1,p2: buf1-A (tile 2i+1)   p3,p4: buf0-B (tile 2i+2)
//     p5,p6: buf0-A (tile 2i+2)   p7,p8: buf1-B (tile 2i+3)
//   Each slot verified against last-reader windows (B read only at the
//   tile's first phase; A read through its last phase).
//   Tile walk flipped: consecutive wgids share the A-panel (2MB, L2-fit),
//   B (Wc, 32MB) streams via L3.
// Swizzle/staging addressing unchanged from R5 (verified, 0 conflicts).
// ---------------------------------------------------------------------------

typedef __attribute__((ext_vector_type(8))) short short8;   // 8 bf16 = 4 VGPRs
typedef __attribute__((ext_vector_type(4))) float f32x4;    // MFMA acc

__device__ __forceinline__ unsigned short f2bf(float f) {
  union { float f; unsigned int u; } c; c.f = f;
  unsigned int u = c.u;
  unsigned int r = (u + 0x7fffu + ((u >> 16) & 1u)) >> 16;  // RNE, finite inputs
  return (unsigned short)r;
}

__device__ __forceinline__ void gl2lds16(const unsigned short* g, unsigned short* l) {
  __builtin_amdgcn_global_load_lds(
      (const __attribute__((address_space(1))) unsigned int*)g,
      (__attribute__((address_space(3))) unsigned int*)l, 16, 0, 0);
}

// Merged prep: blocks [0,8192) cvt x->bf16 (4 float4/thread);
// [8192,12288) Bd; [12288,13312) A^T.
__global__ __launch_bounds__(256) void k_pre(const float* __restrict__ x,
                                             unsigned short* __restrict__ xb,
                                             const float* __restrict__ Bv,
                                             const float* __restrict__ Av,
                                             const float* __restrict__ dv,
                                             const float* __restrict__ bv,
                                             unsigned short* __restrict__ Bd,
                                             unsigned short* __restrict__ AbT) {
  __shared__ float tl[32][33];
  const int blk = blockIdx.x;
  const int tid = threadIdx.x;
  if (blk < 8192) {
#pragma unroll
    for (int s = 0; s < 4; ++s) {
      int i = blk * 1024 + s * 256 + tid;
      const float4 v = ((const float4*)x)[i];
      union { unsigned short u[4]; unsigned long long ll; } o;
      o.u[0] = f2bf(v.x); o.u[1] = f2bf(v.y); o.u[2] = f2bf(v.z); o.u[3] = f2bf(v.w);
      ((unsigned long long*)xb)[i] = o.ll;
    }
  } else if (blk < 12288) {
    // Bd[o][r] = bf16(4 * b[o] * B[o][r] * d[r])
    int idx = (blk - 8192) * 256 + tid;
    int o = idx >> 8, r = idx & 255;
    Bd[idx] = f2bf(4.0f * bv[o] * Bv[idx] * dv[r]);
  } else {
    // AbT[i][r] = bf16(A[r][i]) via padded LDS tile (coalesced both sides)
    int blk2 = blk - 12288;           // 1024 blocks
    int ti = blk2 >> 3;               // i-block, 0..127
    int tr = blk2 & 7;                // r-block, 0..7
#pragma unroll
    for (int s = 0; s < 4; ++s) {
      int r = tr * 32 + s * 8 + (tid >> 5);
      int i = ti * 32 + (tid & 31);
      tl[s * 8 + (tid >> 5)][tid & 31] = Av[(size_t)r * 4096 + i];
    }
    __syncthreads();
#pragma unroll
    for (int s = 0; s < 4; ++s) {
      int iloc = s * 8 + (tid >> 5);
      int rloc = tid & 31;
      AbT[(size_t)(ti * 32 + iloc) * 256 + tr * 32 + rloc] = f2bf(tl[rloc][iloc]);
    }
  }
}

// ---------------------------------------------------------------------------
// C[m][n] = sum_k Amat[m][k]*Bmat[n][k]  (row-major, K contiguous, K%128==0)
// FOLD=1: outB[m*N+n] = bf16(extra[m*N+n] + acc)   (extra = base W)
// FOLD=0: outF[m*N+n] = acc + extra[n]             (extra = bias)
// 256x256 block, 512 thr (8 waves, 2M x 4N), per-wave 128x64 output.
// LDS planes: [buf(2)][khalf(2)][256 rows][32 cols] bf16 per matrix = 128KB.
// ---------------------------------------------------------------------------
template <int FOLD>
__global__ __launch_bounds__(512, 2) void gemm256(const unsigned short* __restrict__ Amat,
                                                  const unsigned short* __restrict__ Bmat,
                                                  int K, int N, int NBX,
                                                  const float* __restrict__ extra,
                                                  float* __restrict__ outF,
                                                  unsigned short* __restrict__ outB) {
  __shared__ __align__(16) unsigned short As[2 * 2 * 8192];   // 64KB
  __shared__ __align__(16) unsigned short Bs[2 * 2 * 8192];   // 64KB

  const int tid  = threadIdx.x;
  const int lane = tid & 63;
  const int wave = tid >> 6;      // 0..7
  const int wm   = wave >> 2;     // 0..1  (M half)
  const int wn   = wave & 3;      // 0..3  (N quarter)
  const int quad = lane >> 4;     // 0..3
  const int m16  = lane & 15;
  const int qsl  = quad ^ ((m16 >> 1) & 3);   // de-swizzled chunk slot

  // XCD-bijective remap (gridDim.x % 8 == 0). bx fast => consecutive wgids
  // share the A-panel (2MB, L2-resident); B streams (L3-resident).
  const int nwg  = gridDim.x;
  const int cpx  = nwg >> 3;
  const int wgid = (blockIdx.x & 7) * cpx + (blockIdx.x >> 3);
  const int bx   = wgid % NBX;
  const int by   = wgid / NBX;
  const int blockM = by * 256;
  const int blockN = bx * 256;

  // Staging: thread covers row r=(tid>>2) (+128 for 2nd load), dest slot
  // c=tid&3 (16B chunks), source chunk q=c^((r>>1)&3)=c^((tid>>3)&3).
  // Dest is linear (base + tid*16B) as global_load_lds requires.
  const int srow = tid >> 2;
  const int sq8  = ((tid & 3) ^ ((tid >> 3) & 3)) * 8;
  const size_t aB0 = (size_t)(blockM + srow) * K + sq8;
  const size_t aB1 = aB0 + (size_t)128 * K;
  const size_t bB0 = (size_t)(blockN + srow) * K + sq8;
  const size_t bB1 = bB0 + (size_t)128 * K;

  const short8* Asv = (const short8*)As;
  const short8* Bsv = (const short8*)Bs;
  // read bases (short8 units within an 8192-elem plane = 1024 units)
  const int aRd = wm * 512 + m16 * 4 + qsl;   // + q*128 + mt*64 + plane*1024
  const int bRd = wn * 256 + m16 * 4 + qsl;   // + nt*64          + plane*1024

  f32x4 acc[8][4];
#pragma unroll
  for (int i = 0; i < 8; ++i)
#pragma unroll
    for (int j = 0; j < 4; ++j) acc[i][j] = (f32x4){0.f, 0.f, 0.f, 0.f};

  short8 afr[4];   // A-frags of current phase's quadrant (kh*2+mt)
  short8 bfr[8];   // B-frags of current tile, full K (kh*4+nt); live 4 phases

#define VM4()  asm volatile("s_waitcnt vmcnt(4)" ::: "memory")
#define VM0()  asm volatile("s_waitcnt vmcnt(0)" ::: "memory")
#define NOPW() ((void)0)

#define ISSUE_A(bufi, kh, koff) do {                                         \
    unsigned short* d_ = As + ((bufi) * 2 + (kh)) * 8192 + tid * 8;          \
    gl2lds16(Amat + aB0 + (koff) + (kh) * 32, d_);                           \
    gl2lds16(Amat + aB1 + (koff) + (kh) * 32, d_ + 4096);                    \
  } while (0)

#define ISSUE_B(bufi, kh, koff) do {                                         \
    unsigned short* d_ = Bs + ((bufi) * 2 + (kh)) * 8192 + tid * 8;          \
    gl2lds16(Bmat + bB0 + (koff) + (kh) * 32, d_);                           \
    gl2lds16(Bmat + bB1 + (koff) + (kh) * 32, d_ + 4096);                    \
  } while (0)

#define RD_B8(Bb) do {                                                       \
    _Pragma("unroll") for (int kh = 0; kh < 2; ++kh)                         \
    _Pragma("unroll") for (int nt = 0; nt < 4; ++nt)                         \
      bfr[kh * 4 + nt] = Bsv[((Bb) * 2 + kh) * 1024 + bRd + nt * 64];        \
  } while (0)

#define RD_A4(Bb, q) do {                                                    \
    _Pragma("unroll") for (int kh = 0; kh < 2; ++kh)                         \
    _Pragma("unroll") for (int mt = 0; mt < 2; ++mt)                         \
      afr[kh * 2 + mt] =                                                     \
          Asv[((Bb) * 2 + kh) * 1024 + aRd + (q) * 128 + mt * 64];           \
  } while (0)

#define MM16(q) do {                                                         \
    _Pragma("unroll") for (int kh = 0; kh < 2; ++kh)                         \
    _Pragma("unroll") for (int mt = 0; mt < 2; ++mt)                         \
    _Pragma("unroll") for (int nt = 0; nt < 4; ++nt)                         \
      acc[(q) * 2 + mt][nt] = __builtin_amdgcn_mfma_f32_16x16x32_bf16(       \
          afr[kh * 2 + mt], bfr[kh * 4 + nt], acc[(q) * 2 + mt][nt], 0, 0, 0);\
  } while (0)

// One phase: reads pre-barrier (latency hides under barrier#1 while sibling
// waves finish previous MFMA cluster); stage issued pre-wait so counted
// vmcnt survivors are exactly this+prev phase's units; lgkmcnt(0)+
// sched_barrier pins MFMA below the wait (rule #18); barrier#2 locksteps.
#define PH(Bb, q, STAGE, WAITOPT) do {                                       \
    if ((q) == 0) { RD_B8(Bb); }                                             \
    RD_A4(Bb, q);                                                            \
    STAGE;                                                                   \
    WAITOPT;                                                                 \
    asm volatile("s_barrier" ::: "memory");                                  \
    asm volatile("s_waitcnt lgkmcnt(0)" ::: "memory");                       \
    __builtin_amdgcn_sched_barrier(0);                                       \
    __builtin_amdgcn_s_setprio(1);                                           \
    MM16(q);                                                                 \
    __builtin_amdgcn_s_setprio(0);                                           \
    __builtin_amdgcn_sched_barrier(0);                                       \
    asm volatile("s_barrier" ::: "memory");                                  \
  } while (0)

  // Prologue: tile0 all 4 units + tile1's B units; vmcnt(4) keeps tile1-B
  // in flight, publishes tile0.
  ISSUE_A(0, 0, (size_t)0);  ISSUE_A(0, 1, (size_t)0);
  ISSUE_B(0, 0, (size_t)0);  ISSUE_B(0, 1, (size_t)0);
  ISSUE_B(1, 0, (size_t)64); ISSUE_B(1, 1, (size_t)64);
  VM4();
  asm volatile("s_barrier" ::: "memory");

  const int NT = K >> 6;        // 64-wide K-tiles (even, >= 4 at both call sites)
  const int NI = NT >> 1;       // iterations of 2 tiles
  size_t ko = 0;
  for (int i = 0; i < NI - 1; ++i) {
    PH(0, 0, ISSUE_A(1, 0, ko + 64),  NOPW());
    PH(0, 1, ISSUE_A(1, 1, ko + 64),  NOPW());
    PH(0, 2, ISSUE_B(0, 0, ko + 128), NOPW());
    PH(0, 3, ISSUE_B(0, 1, ko + 128), VM4());   // publishes buf1 (tile 2i+1)
    PH(1, 0, ISSUE_A(0, 0, ko + 128), NOPW());
    PH(1, 1, ISSUE_A(0, 1, ko + 128), NOPW());
    PH(1, 2, ISSUE_B(1, 0, ko + 192), NOPW());
    PH(1, 3, ISSUE_B(1, 1, ko + 192), VM4());   // publishes buf0 (tile 2i+2)
    ko += 128;
  }
  // Last iteration (tiles NT-2, NT-1): only tile NT-1's A left to stage.
  PH(0, 0, ISSUE_A(1, 0, ko + 64), NOPW());
  PH(0, 1, ISSUE_A(1, 1, ko + 64), NOPW());
  PH(0, 2, NOPW(), NOPW());
  PH(0, 3, NOPW(), VM0());                      // publishes buf1 (tile NT-1)
  PH(1, 0, NOPW(), NOPW());
  PH(1, 1, NOPW(), NOPW());
  PH(1, 2, NOPW(), NOPW());
  PH(1, 3, NOPW(), NOPW());

#undef VM4
#undef VM0
#undef NOPW
#undef ISSUE_A
#undef ISSUE_B
#undef RD_B8
#undef RD_A4
#undef MM16
#undef PH

  // C/D layout: col = lane&15, row = quad*4 + reg  [verified m89/m91]
#pragma unroll
  for (int mt = 0; mt < 8; ++mt) {
    const int row0 = blockM + wm * 128 + mt * 16 + quad * 4;
#pragma unroll
    for (int nt = 0; nt < 4; ++nt) {
      const int col = blockN + wn * 64 + nt * 16 + m16;
      f32x4 v = acc[mt][nt];
      if (FOLD) {
#pragma unroll
        for (int r = 0; r < 4; ++r) {
          size_t o = (size_t)(row0 + r) * N + col;
          outB[o] = f2bf(extra[o] + v[r]);
        }
      } else {
        const float bb = extra[col];
#pragma unroll
        for (int r = 0; r < 4; ++r) {
          size_t o = (size_t)(row0 + r) * N + col;
          outF[o] = v[r] + bb;
        }
      }
    }
  }
}

extern "C" void kernel_launch(void* const* d_in, const int* in_sizes, int n_in,
                              void* d_out, int out_size, void* d_ws, size_t ws_size,
                              hipStream_t stream) {
  const float* x    = (const float*)d_in[0];  // (8192, 4096)
  const float* W    = (const float*)d_in[1];  // (4096, 4096)
  const float* bias = (const float*)d_in[2];  // (4096,)
  const float* A    = (const float*)d_in[3];  // (256, 4096)
  const float* B    = (const float*)d_in[4];  // (4096, 256)
  const float* dv   = (const float*)d_in[5];  // (256,)
  const float* bv   = (const float*)d_in[6];  // (4096,)
  float* out = (float*)d_out;                 // (8192, 4096)

  char* ws = (char*)d_ws;
  unsigned short* xb  = (unsigned short*)ws;                        // 64MB x bf16
  unsigned short* Wc  = (unsigned short*)(ws + (size_t)(64 << 20)); // 32MB W+delta bf16
  unsigned short* Bd  = (unsigned short*)(ws + (size_t)(96 << 20)); // 2MB
  unsigned short* AbT = (unsigned short*)(ws + (size_t)(98 << 20)); // 2MB

  // 1. cvt + Bd + A^T in one launch
  hipLaunchKernelGGL(k_pre, dim3(13312), dim3(256), 0, stream,
                     x, xb, B, A, dv, bv, Bd, AbT);
  // 2. Wc = bf16(W + Bd @ AbT^T)   M=N=4096, K=256  (16x16 tiles, 256 blocks)
  hipLaunchKernelGGL((gemm256<1>), dim3(256), dim3(512), 0, stream,
                     Bd, AbT, 256, 4096, 16, W, (float*)nullptr, Wc);
  // 3. out = xb @ Wc^T + bias      M=8192, N=4096, K=4096  (16x32 tiles, 512 blocks)
  hipLaunchKernelGGL((gemm256<0>), dim3(512), dim3(512), 0, stream,
                     xb, Wc, 4096, 4096, 16, bias, out, (unsigned short*)nullptr);
}

// Round 5
// 540.843 us; speedup vs baseline: 1.0233x; 1.0233x over previous
//
#include <hip/hip_runtime.h>

// ---------------------------------------------------------------------------
// VeRA Linear: y = x @ (W + 4*diag(b) B diag(d) A)^T + bias
// T=8192, IN=OUT=4096, R=256, fp32 in/out.
// R8 (= R7 resubmit after second container infra failure; audited clean:
// no deadlock path, queue ledger + WAR windows + OOB re-verified):
// single-barrier-per-phase pipeline (fixes R6's lockstep serialization).
//   Phase p: bar; lgkm0; sched_barrier; ISSUE(slot_p); setprio(1); 16 MFMA;
//            setprio(0); tail ds_reads for phase p+1 (ping-pong regs);
//            [vmcnt(4) pre-bar at p4/p8].
//   Tail reads execute on the LDS pipe while the matrix pipe drains and the
//   wave waits at the next barrier -> read latency hidden in 6/8 phases.
//   Only q0 phases (p1/p5: B8+A4 reads) are exposed post-bar (publication
//   of DMA'd LDS requires the barrier; per-wave vmcnt can't publish other
//   waves' loads).
//   Staging ledger (steady iter, tiles 2i/2i+1 in buf0/buf1):
//     p1: A-buf1 (tile 2i+1, 4 loads)   p2,p3: B-buf0 (tile 2i+2, 2+2)
//     p5: A-buf0 (tile 2i+2, 4)         p7,p8: B-buf1 (tile 2i+3, 2+2)
//   Every overwrite is >=2 barriers after its region's last reader (B-LDS is
//   dead after q0 -> regs; A-planes read through q3).
//   vmcnt(4)@p4 drains {B1prev,A1} -> buf1 published at bar(p5);
//   vmcnt(4)@p8 drains {B0next,A0next} -> buf0 published at bar(p1').
//   Invariant: 4 loads in flight entering each iteration.
// Swizzle/staging addressing + XCD/A-panel swizzle unchanged (verified,
// 0 bank conflicts, FETCH halved in R6).
// ---------------------------------------------------------------------------

typedef __attribute__((ext_vector_type(8))) short short8;   // 8 bf16 = 4 VGPRs
typedef __attribute__((ext_vector_type(4))) float f32x4;    // MFMA acc

__device__ __forceinline__ unsigned short f2bf(float f) {
  union { float f; unsigned int u; } c; c.f = f;
  unsigned int u = c.u;
  unsigned int r = (u + 0x7fffu + ((u >> 16) & 1u)) >> 16;  // RNE, finite inputs
  return (unsigned short)r;
}

__device__ __forceinline__ void gl2lds16(const unsigned short* g, unsigned short* l) {
  __builtin_amdgcn_global_load_lds(
      (const __attribute__((address_space(1))) unsigned int*)g,
      (__attribute__((address_space(3))) unsigned int*)l, 16, 0, 0);
}

// Merged prep: blocks [0,8192) cvt x->bf16 (4 float4/thread);
// [8192,12288) Bd; [12288,13312) A^T.
__global__ __launch_bounds__(256) void k_pre(const float* __restrict__ x,
                                             unsigned short* __restrict__ xb,
                                             const float* __restrict__ Bv,
                                             const float* __restrict__ Av,
                                             const float* __restrict__ dv,
                                             const float* __restrict__ bv,
                                             unsigned short* __restrict__ Bd,
                                             unsigned short* __restrict__ AbT) {
  __shared__ float tl[32][33];
  const int blk = blockIdx.x;
  const int tid = threadIdx.x;
  if (blk < 8192) {
#pragma unroll
    for (int s = 0; s < 4; ++s) {
      int i = blk * 1024 + s * 256 + tid;
      const float4 v = ((const float4*)x)[i];
      union { unsigned short u[4]; unsigned long long ll; } o;
      o.u[0] = f2bf(v.x); o.u[1] = f2bf(v.y); o.u[2] = f2bf(v.z); o.u[3] = f2bf(v.w);
      ((unsigned long long*)xb)[i] = o.ll;
    }
  } else if (blk < 12288) {
    // Bd[o][r] = bf16(4 * b[o] * B[o][r] * d[r])
    int idx = (blk - 8192) * 256 + tid;
    int o = idx >> 8, r = idx & 255;
    Bd[idx] = f2bf(4.0f * bv[o] * Bv[idx] * dv[r]);
  } else {
    // AbT[i][r] = bf16(A[r][i]) via padded LDS tile (coalesced both sides)
    int blk2 = blk - 12288;           // 1024 blocks
    int ti = blk2 >> 3;               // i-block, 0..127
    int tr = blk2 & 7;                // r-block, 0..7
#pragma unroll
    for (int s = 0; s < 4; ++s) {
      int r = tr * 32 + s * 8 + (tid >> 5);
      int i = ti * 32 + (tid & 31);
      tl[s * 8 + (tid >> 5)][tid & 31] = Av[(size_t)r * 4096 + i];
    }
    __syncthreads();
#pragma unroll
    for (int s = 0; s < 4; ++s) {
      int iloc = s * 8 + (tid >> 5);
      int rloc = tid & 31;
      AbT[(size_t)(ti * 32 + iloc) * 256 + tr * 32 + rloc] = f2bf(tl[rloc][iloc]);
    }
  }
}

// ---------------------------------------------------------------------------
// C[m][n] = sum_k Amat[m][k]*Bmat[n][k]  (row-major, K contiguous, K%128==0)
// FOLD=1: outB[m*N+n] = bf16(extra[m*N+n] + acc)   (extra = base W)
// FOLD=0: outF[m*N+n] = acc + extra[n]             (extra = bias)
// 256x256 block, 512 thr (8 waves, 2M x 4N), per-wave 128x64 output.
// LDS planes: [buf(2)][khalf(2)][256 rows][32 cols] bf16 per matrix = 128KB.
// ---------------------------------------------------------------------------
template <int FOLD>
__global__ __launch_bounds__(512, 2) void gemm256(const unsigned short* __restrict__ Amat,
                                                  const unsigned short* __restrict__ Bmat,
                                                  int K, int N, int NBX,
                                                  const float* __restrict__ extra,
                                                  float* __restrict__ outF,
                                                  unsigned short* __restrict__ outB) {
  __shared__ __align__(16) unsigned short As[2 * 2 * 8192];   // 64KB
  __shared__ __align__(16) unsigned short Bs[2 * 2 * 8192];   // 64KB

  const int tid  = threadIdx.x;
  const int lane = tid & 63;
  const int wave = tid >> 6;      // 0..7
  const int wm   = wave >> 2;     // 0..1  (M half)
  const int wn   = wave & 3;      // 0..3  (N quarter)
  const int quad = lane >> 4;     // 0..3
  const int m16  = lane & 15;
  const int qsl  = quad ^ ((m16 >> 1) & 3);   // de-swizzled chunk slot

  // XCD-bijective remap (gridDim.x % 8 == 0). bx fast => consecutive wgids
  // share the A-panel (2MB, L2-resident); B streams (L3-resident).
  const int nwg  = gridDim.x;
  const int cpx  = nwg >> 3;
  const int wgid = (blockIdx.x & 7) * cpx + (blockIdx.x >> 3);
  const int bx   = wgid % NBX;
  const int by   = wgid / NBX;
  const int blockM = by * 256;
  const int blockN = bx * 256;

  // Staging: thread covers row r=(tid>>2) (+128 for 2nd load), dest slot
  // c=tid&3 (16B chunks), source chunk q=c^((r>>1)&3)=c^((tid>>3)&3).
  // Dest is linear (base + tid*16B) as global_load_lds requires.
  const int srow = tid >> 2;
  const int sq8  = ((tid & 3) ^ ((tid >> 3) & 3)) * 8;
  const size_t aB0 = (size_t)(blockM + srow) * K + sq8;
  const size_t aB1 = aB0 + (size_t)128 * K;
  const size_t bB0 = (size_t)(blockN + srow) * K + sq8;
  const size_t bB1 = bB0 + (size_t)128 * K;

  const short8* Asv = (const short8*)As;
  const short8* Bsv = (const short8*)Bs;
  // read bases (short8 units within an 8192-elem plane = 1024 units)
  const int aRd = wm * 512 + m16 * 4 + qsl;   // + q*128 + mt*64 + plane*1024
  const int bRd = wn * 256 + m16 * 4 + qsl;   // + nt*64          + plane*1024

  f32x4 acc[8][4];
#pragma unroll
  for (int i = 0; i < 8; ++i)
#pragma unroll
    for (int j = 0; j < 4; ++j) acc[i][j] = (f32x4){0.f, 0.f, 0.f, 0.f};

  // Ping-pong fragment registers (static names, no runtime indexing).
  short8 afr0[4], afr1[4];   // A-frags of a quadrant (kh*2+mt)
  short8 bfr0[8], bfr1[8];   // B-frags of a tile, full K (kh*4+nt)

#define BAR()   asm volatile("s_barrier" ::: "memory")
#define LGKM0() asm volatile("s_waitcnt lgkmcnt(0)" ::: "memory")
#define VMW4()  asm volatile("s_waitcnt vmcnt(4)" ::: "memory")
#define VMW0()  asm volatile("s_waitcnt vmcnt(0)" ::: "memory")
#define SBAR()  __builtin_amdgcn_sched_barrier(0)
#define PRIO1() __builtin_amdgcn_s_setprio(1)
#define PRIO0() __builtin_amdgcn_s_setprio(0)

#define ISSUE_A(bufi, kh, koff) do {                                         \
    unsigned short* d_ = As + ((bufi) * 2 + (kh)) * 8192 + tid * 8;          \
    gl2lds16(Amat + aB0 + (koff) + (kh) * 32, d_);                           \
    gl2lds16(Amat + aB1 + (koff) + (kh) * 32, d_ + 4096);                    \
  } while (0)

#define ISSUE_B(bufi, kh, koff) do {                                         \
    unsigned short* d_ = Bs + ((bufi) * 2 + (kh)) * 8192 + tid * 8;          \
    gl2lds16(Bmat + bB0 + (koff) + (kh) * 32, d_);                           \
    gl2lds16(Bmat + bB1 + (koff) + (kh) * 32, d_ + 4096);                    \
  } while (0)

#define RDB8(dst, Bb) do {                                                   \
    _Pragma("unroll") for (int kh = 0; kh < 2; ++kh)                         \
    _Pragma("unroll") for (int nt = 0; nt < 4; ++nt)                         \
      dst[kh * 4 + nt] = Bsv[((Bb) * 2 + kh) * 1024 + bRd + nt * 64];        \
  } while (0)

#define RDA4(dst, Bb, q) do {                                                \
    _Pragma("unroll") for (int kh = 0; kh < 2; ++kh)                         \
    _Pragma("unroll") for (int mt = 0; mt < 2; ++mt)                         \
      dst[kh * 2 + mt] =                                                     \
          Asv[((Bb) * 2 + kh) * 1024 + aRd + (q) * 128 + mt * 64];           \
  } while (0)

#define MM16(q, AF, BF) do {                                                 \
    PRIO1();                                                                 \
    _Pragma("unroll") for (int kh = 0; kh < 2; ++kh)                         \
    _Pragma("unroll") for (int mt = 0; mt < 2; ++mt)                         \
    _Pragma("unroll") for (int nt = 0; nt < 4; ++nt)                         \
      acc[(q) * 2 + mt][nt] = __builtin_amdgcn_mfma_f32_16x16x32_bf16(       \
          AF[kh * 2 + mt], BF[kh * 4 + nt], acc[(q) * 2 + mt][nt], 0, 0, 0); \
    PRIO0();                                                                 \
  } while (0)

  // Prologue: buf0 A+B (tile0, 8 loads) + buf1-B (tile1, 4 loads);
  // vmcnt(4) drains buf0, keeps buf1-B in flight -> steady invariant.
  ISSUE_A(0, 0, (size_t)0);  ISSUE_A(0, 1, (size_t)0);
  ISSUE_B(0, 0, (size_t)0);  ISSUE_B(0, 1, (size_t)0);
  ISSUE_B(1, 0, (size_t)64); ISSUE_B(1, 1, (size_t)64);
  VMW4();

  const int NT = K >> 6;        // 64-wide K-tiles (even, >= 4 at both call sites)
  const int NI = NT >> 1;       // iterations of 2 tiles
  size_t ko = 0;
  for (int i = 0; i < NI - 1; ++i) {
    // ---- P1 (buf0 q0): exposed q0 reads; stage A-buf1 (tile 2i+1) ----
    BAR();
    RDB8(bfr0, 0); RDA4(afr0, 0, 0);
    ISSUE_A(1, 0, ko + 64); ISSUE_A(1, 1, ko + 64);
    LGKM0(); SBAR();
    MM16(0, afr0, bfr0);
    RDA4(afr1, 0, 1);
    // ---- P2: stage B-buf0 k0 (tile 2i+2) ----
    BAR(); ISSUE_B(0, 0, ko + 128); LGKM0(); SBAR();
    MM16(1, afr1, bfr0);
    RDA4(afr0, 0, 2);
    // ---- P3: stage B-buf0 k1 ----
    BAR(); ISSUE_B(0, 1, ko + 128); LGKM0(); SBAR();
    MM16(2, afr0, bfr0);
    RDA4(afr1, 0, 3);
    // ---- P4: publish buf1 {B@prev p7/p8, A@p1} ----
    BAR(); LGKM0(); SBAR();
    MM16(3, afr1, bfr0);
    VMW4();
    // ---- P5 (buf1 q0): exposed q0 reads; stage A-buf0 (tile 2i+2) ----
    BAR();
    RDB8(bfr1, 1); RDA4(afr0, 1, 0);
    ISSUE_A(0, 0, ko + 128); ISSUE_A(0, 1, ko + 128);
    LGKM0(); SBAR();
    MM16(0, afr0, bfr1);
    RDA4(afr1, 1, 1);
    // ---- P6 ----
    BAR(); LGKM0(); SBAR();
    MM16(1, afr1, bfr1);
    RDA4(afr0, 1, 2);
    // ---- P7: stage B-buf1 k0 (tile 2i+3) ----
    BAR(); ISSUE_B(1, 0, ko + 192); LGKM0(); SBAR();
    MM16(2, afr0, bfr1);
    RDA4(afr1, 1, 3);
    // ---- P8: publish buf0 {B@p2/p3, A@p5} ----
    BAR(); ISSUE_B(1, 1, ko + 192); LGKM0(); SBAR();
    MM16(3, afr1, bfr1);
    VMW4();
    ko += 128;
  }
  // ---- Final iteration (tiles NT-2 in buf0, NT-1 in buf1) ----
  BAR();
  RDB8(bfr0, 0); RDA4(afr0, 0, 0);
  ISSUE_A(1, 0, ko + 64); ISSUE_A(1, 1, ko + 64);   // tile NT-1's A
  LGKM0(); SBAR();
  MM16(0, afr0, bfr0);
  RDA4(afr1, 0, 1);
  BAR(); LGKM0(); SBAR();
  MM16(1, afr1, bfr0);
  RDA4(afr0, 0, 2);
  BAR(); LGKM0(); SBAR();
  MM16(2, afr0, bfr0);
  RDA4(afr1, 0, 3);
  BAR(); LGKM0(); SBAR();
  MM16(3, afr1, bfr0);
  VMW0();                                            // publish buf1 fully
  BAR();
  RDB8(bfr1, 1); RDA4(afr0, 1, 0);
  LGKM0(); SBAR();
  MM16(0, afr0, bfr1);
  RDA4(afr1, 1, 1);
  BAR(); LGKM0(); SBAR();
  MM16(1, afr1, bfr1);
  RDA4(afr0, 1, 2);
  BAR(); LGKM0(); SBAR();
  MM16(2, afr0, bfr1);
  RDA4(afr1, 1, 3);
  BAR(); LGKM0(); SBAR();
  MM16(3, afr1, bfr1);

#undef BAR
#undef LGKM0
#undef VMW4
#undef VMW0
#undef SBAR
#undef PRIO1
#undef PRIO0
#undef ISSUE_A
#undef ISSUE_B
#undef RDB8
#undef RDA4
#undef MM16

  // C/D layout: col = lane&15, row = quad*4 + reg  [verified m89/m91]
#pragma unroll
  for (int mt = 0; mt < 8; ++mt) {
    const int row0 = blockM + wm * 128 + mt * 16 + quad * 4;
#pragma unroll
    for (int nt = 0; nt < 4; ++nt) {
      const int col = blockN + wn * 64 + nt * 16 + m16;
      f32x4 v = acc[mt][nt];
      if (FOLD) {
#pragma unroll
        for (int r = 0; r < 4; ++r) {
          size_t o = (size_t)(row0 + r) * N + col;
          outB[o] = f2bf(extra[o] + v[r]);
        }
      } else {
        const float bb = extra[col];
#pragma unroll
        for (int r = 0; r < 4; ++r) {
          size_t o = (size_t)(row0 + r) * N + col;
          outF[o] = v[r] + bb;
        }
      }
    }
  }
}

extern "C" void kernel_launch(void* const* d_in, const int* in_sizes, int n_in,
                              void* d_out, int out_size, void* d_ws, size_t ws_size,
                              hipStream_t stream) {
  const float* x    = (const float*)d_in[0];  // (8192, 4096)
  const float* W    = (const float*)d_in[1];  // (4096, 4096)
  const float* bias = (const float*)d_in[2];  // (4096,)
  const float* A    = (const float*)d_in[3];  // (256, 4096)
  const float* B    = (const float*)d_in[4];  // (4096, 256)
  const float* dv   = (const float*)d_in[5];  // (256,)
  const float* bv   = (const float*)d_in[6];  // (4096,)
  float* out = (float*)d_out;                 // (8192, 4096)

  char* ws = (char*)d_ws;
  unsigned short* xb  = (unsigned short*)ws;                        // 64MB x bf16
  unsigned short* Wc  = (unsigned short*)(ws + (size_t)(64 << 20)); // 32MB W+delta bf16
  unsigned short* Bd  = (unsigned short*)(ws + (size_t)(96 << 20)); // 2MB
  unsigned short* AbT = (unsigned short*)(ws + (size_t)(98 << 20)); // 2MB

  // 1. cvt + Bd + A^T in one launch
  hipLaunchKernelGGL(k_pre, dim3(13312), dim3(256), 0, stream,
                     x, xb, B, A, dv, bv, Bd, AbT);
  // 2. Wc = bf16(W + Bd @ AbT^T)   M=N=4096, K=256  (16x16 tiles, 256 blocks)
  hipLaunchKernelGGL((gemm256<1>), dim3(256), dim3(512), 0, stream,
                     Bd, AbT, 256, 4096, 16, W, (float*)nullptr, Wc);
  // 3. out = xb @ Wc^T + bias      M=8192, N=4096, K=4096  (16x32 tiles, 512 blocks)
  hipLaunchKernelGGL((gemm256<0>), dim3(512), dim3(512), 0, stream,
                     xb, Wc, 4096, 4096, 16, bias, out, (unsigned short*)nullptr);
}